// Round 11
// baseline (227.068 us; speedup 1.0000x reference)
//
#include <hip/hip_runtime.h>

typedef __bf16 bf16x8 __attribute__((ext_vector_type(8)));
typedef __bf16 bf16x4 __attribute__((ext_vector_type(4)));
typedef float f32x4 __attribute__((ext_vector_type(4)));
typedef unsigned long long u64;

#define NCH 8            // row-chunks per recurrence
#define CELLS 16         // rows per chunk
#define NG 256           // 4 gates * 64 units
#define L2E 1.44269504089f
#define RDEPTH 16                       // ring depth (tag mod 16)
#define NLINK (16 * 7)                  // (g, producer ch 0..6)
#define RING_U64 (NLINK * RDEPTH * 64)  // 896 KiB
#define PROG_OFF (RING_U64 * 8)         // byte offset of progress flags

__device__ __forceinline__ unsigned short f2bfbits(float f) {
  __bf16 b = (__bf16)f;
  return __builtin_bit_cast(unsigned short, b);
}
__device__ __forceinline__ float bfbits2f(unsigned short s) {
  return (float)__builtin_bit_cast(__bf16, s);
}
// LDS-only barrier: vmcnt stays in flight (out stores, x loads, ring ops)
__device__ __forceinline__ void barrier_lds() {
  asm volatile("s_waitcnt lgkmcnt(0)" ::: "memory");
  __builtin_amdgcn_s_barrier();
}
// 16B-granule XOR swizzle for 128B bf16 rows (row 0 identity -> linear).
__device__ __forceinline__ int hix(int row, int byteoff) {
  return row * 128 + (byteoff ^ ((row & 7) << 4));
}

// ROW-partitioned 2D-LSTM pipeline; WAVE-SPECIALIZED single-barrier step.
// R10 base (verified protocol). R11 targets the COMPUTE WAVE'S SERIAL
// CHAIN (R10 showed helper work/LDS traffic are not the limiter):
//  - Wr MFMAs as 8 dual 2-deep chains: hi chained from C=accA, lo from a
//    persistent zero register (C is just a register read -> no per-step
//    acc-init movs), merged with 4 f32x4 adds. Halves exposed MFMA dep
//    latency on the post-barrier path.
//  - bias f32x4 (bvec) passed directly as C of the first shadow/prologue
//    MFMA: kills 16 v_mov per step.
//  - epilogue: all 16 independent gate exp2s batched up front (trans pipe
//    fills while j=3's dependent cn/e5/hn chain resolves -> publish still
//    early); P-row writes interleaved into the j loop (row j+1 stored as
//    soon as hcur[j] is ready) so the pre-barrier lgkm drain overlaps.
//  - gh2 carried in a register (it is last step's gh1).
// Block = (chunk ch, recurrence g), 512 thr = 8 waves (2/SIMD):
//   waves 0-3 (compute): P read -> 16 Wr MFMA -> batched LSTM epilogue
//     (j=3 first -> DIRECT ring publish + early shuffles) -> interleaved
//     presum/P-writes -> out stores -> shadow accA(d+1)=b+x(d+1)@Wk.
//   waves 4-7 (helper): stage x(d+3)->xt tri-buf, prefetch x(d+4);
//     waves 4/5 alternate parity: resolve ring tag d+1 (issue-early /
//     resolve-late) -> gbh/gbc, prog; wave 6 pre-validates ring-wrap gate.
__global__ __launch_bounds__(512, 1) void mdrnn_kernel(
    const float* __restrict__ x, const float* __restrict__ Wk,
    const float* __restrict__ Wr, const float* __restrict__ bias,
    float* __restrict__ out, char* __restrict__ ws) {
  __shared__ __align__(16) unsigned char xt[3][CELLS * 128];    // 6 KiB
  __shared__ __align__(16) unsigned char Pbuf[2][CELLS * 128];  // 4 KiB
  __shared__ __align__(16) unsigned char gbh[8 * 128];          // 1 KiB
  __shared__ __align__(16) float gbc[8 * 64];                   // 2 KiB

  u64* __restrict__ ring = (u64*)ws;
  int* __restrict__ prog = (int*)(ws + PROG_OFF);  // 16-int (64B) stride

  const int tid = threadIdx.x;
  const bool isComp = (tid < 256);
  const int L = tid & 63;
  const int lo16 = L & 15;
  const int hi16 = L >> 4;
  const int wq = (tid >> 6) & 3;     // wave id within compute/helper group
  const int u = wq * 16 + lo16;      // unit-group index (both roles)
  const int hm0 = (tid >> 4) & 15;   // helper: staged row
  const int hq16 = tid & 15;         // helper: channel quad

  const int ch = blockIdx.x >> 4;   // bx%8 == g%8 -> chain on one XCD
  const int g = blockIdx.x & 15;
  const int f = g >> 2;
  const int bb = g & 3;
  const int fh = (f >> 1) & 1;
  const int fw = f & 1;
  const int R0 = ch * CELLS;
  const int D1 = R0 + 142;
  const int linkDn = g * 7 + ch - 1;
  const int linkUp = g * 7 + ch;

  for (int i = tid; i < 3 * CELLS * 32; i += 512) ((int*)xt)[i] = 0;
  for (int i = tid; i < 2 * CELLS * 32; i += 512) ((int*)Pbuf)[i] = 0;
  for (int i = tid; i < 8 * 32; i += 512) ((int*)gbh)[i] = 0;
  for (int i = tid; i < 8 * 64; i += 512) gbc[i] = 0.f;

  // ---- compute-wave constants (helpers need no weights) ----
  float bsc[4] = {0.f, 0.f, 0.f, 0.f};
  bf16x8 wkh[4][2], wrh[4][2], wrl[4][2];
  int oidx[4];
  int oStep = 0, cbase = 0;
  int o_ph0 = 0, o_ph1 = 0;
  int o_pw[4] = {0, 0, 0, 0};
  if (isComp) {
    const float* Wrf = Wr + f * (64 * NG);
    const float* Wkf = Wk + f * (64 * NG);
#pragma unroll
    for (int t = 0; t < 4; ++t) {
      const float st = (t == 2) ? (2.f * L2E) : L2E;
      bsc[t] = bias[f * NG + t * 64 + u] * st;
#pragma unroll
      for (int kt = 0; kt < 2; ++kt)
#pragma unroll
        for (int jj = 0; jj < 8; ++jj) {
          int k = kt * 32 + hi16 * 8 + jj;
          float vr = Wrf[k * NG + t * 64 + u] * st;
          __bf16 vh = (__bf16)vr;
          wrh[t][kt][jj] = vh;
          wrl[t][kt][jj] = (__bf16)(vr - (float)vh);
          wkh[t][kt][jj] = (__bf16)(Wkf[k * NG + t * 64 + u] * st);
        }
    }
    const int ccStep = fw ? -1 : 1;
#pragma unroll
    for (int j = 0; j < 4; ++j) {
      int ro = R0 + hi16 * 4 + j;
      int rr = fh ? 127 - ro : ro;
      int c0 = R0 - ro;
      oidx[j] = ((bb * 128 + rr) * 128 + (fw ? 127 - c0 : c0)) * NG + f * 64 + u;
      o_pw[j] = hix(hi16 * 4 + j, u * 2);
    }
    oStep = ccStep * NG;
    cbase = -hi16 * 4;
    o_ph0 = hix(lo16, hi16 * 16);       // presummed A-row lo16, k 0..31
    o_ph1 = hix(lo16, 64 + hi16 * 16);  // k 32..63
  }
  const int o_ax0 = hix(lo16, hi16 * 16);
  const int o_ax1 = hix(lo16, 64 + hi16 * 16);

  // ---- helper-wave x addressing ----
  const int ccStepH = fw ? -1 : 1;
  const int rx = R0 + hm0;
  const int rrx = fh ? 127 - rx : rx;
  int cx = R0 - rx;
  int xidx = ((bb * 128 + rrx) * 128 + (fw ? 127 - cx : cx)) * 64 + hq16 * 4;
  const int xStep = ccStepH * 64;
  float4 px;
  bool pxv = false;
  auto ldg = [&]() {
    pxv = ((unsigned)cx <= 127u);
    px = make_float4(0.f, 0.f, 0.f, 0.f);
    if (pxv) px = *(const float4*)(x + xidx);
    xidx += xStep;
    ++cx;
  };
  auto stx = [&](unsigned char* buf) {
    if (pxv) {
      bf16x4 pk;
      pk[0] = (__bf16)px.x; pk[1] = (__bf16)px.y;
      pk[2] = (__bf16)px.z; pk[3] = (__bf16)px.w;
      *(bf16x4*)(buf + hix(hm0, hq16 * 8)) = pk;
    }
  };

  __syncthreads();  // S0: zero-init visible

  if (!isComp) {
    ldg();                       // px = x(R0)
    stx(&xt[R0 % 3][0]);
    ldg();                       // px = x(R0+1)
  }
  __syncthreads();  // S1: xt(R0) visible

  if (!isComp) {
    stx(&xt[(R0 + 1) % 3][0]);   // stage x(R0+1)
    ldg();                       // px = x(R0+2)
    // pre-loop poll (wave 4): ONLY tags R0-1, R0; in-loop parity polls
    // take over from q=R0+1 (fill-lag unpinned, R8).
    if (wq == 0 && ch > 0) {
#pragma unroll
      for (int k = 0; k < 2; ++k) {
        const int q = R0 - 1 + k;
        u64* src = ring + ((linkDn * RDEPTH + (q & (RDEPTH - 1))) << 6) + L;
        u64 v;
        int spin = 0;
        for (;;) {
          v = __hip_atomic_load(src, __ATOMIC_RELAXED, __HIP_MEMORY_SCOPE_AGENT);
          if ((unsigned short)(v >> 48) == (unsigned short)q ||
              spin >= (1 << 22))
            break;
          ++spin;
          __builtin_amdgcn_s_sleep(1);
        }
        *(unsigned short*)(gbh + (q & 7) * 128 + L * 2) =
            (unsigned short)(v >> 32);
        gbc[(q & 7) * 64 + L] = __uint_as_float((unsigned)v);
        if (k == 0)  // P(R0-1)[row0] = guard h (scale 1; rest stays zero)
          *(unsigned short*)(&Pbuf[(R0 + 1) & 1][0] + L * 2) =
              (unsigned short)(v >> 32);
      }
      if (L == 0)
        __hip_atomic_store(&prog[linkDn * 16], R0, __ATOMIC_RELAXED,
                           __HIP_MEMORY_SCOPE_AGENT);
    }
  }
  __syncthreads();  // S2: xt(R0+1), gbh/gbc, P-init visible

  // ---- compute-wave carried state ----
  f32x4 zacc[4];
  f32x4 bvec[4];
  const f32x4 zerov = (f32x4){0.f, 0.f, 0.f, 0.f};
  float hnprev[4];  // this lane's h(d-1)[rows lm] (masked)
  float csj[4];     // presummed c for the CURRENT step
  float puv[4];     // carried c_ul = prev step's c_up
  float ghp = 0.f;  // carried guard h of tag d-1 (= prev step's gh1)
  int gateSeen = 0;  // helper wave 6 only
  if (isComp) {
#pragma unroll
    for (int t = 0; t < 4; ++t)
      bvec[t] = (f32x4){bsc[t], bsc[t], bsc[t], bsc[t]};
    // prologue accA(R0) = b + x(R0)@Wk (C=bvec directly; no init movs)
    const unsigned char* xp = &xt[R0 % 3][0];
    bf16x8 a0 = *(const bf16x8*)(xp + o_ax0);
    bf16x8 a1 = *(const bf16x8*)(xp + o_ax1);
#pragma unroll
    for (int t = 0; t < 4; ++t) {
      zacc[t] = __builtin_amdgcn_mfma_f32_16x16x32_bf16(a0, wkh[t][0], bvec[t], 0, 0, 0);
      zacc[t] = __builtin_amdgcn_mfma_f32_16x16x32_bf16(a1, wkh[t][1], zacc[t], 0, 0, 0);
    }
    const float cu0 = gbc[((R0 - 1) & 7) * 64 + u];  // zero for ch==0
    ghp = bfbits2f(*(const unsigned short*)(gbh + ((R0 - 1) & 7) * 128 + u * 2));
#pragma unroll
    for (int j = 0; j < 4; ++j) {
      const float ci = (hi16 == 0 && j == 0) ? cu0 : 0.f;
      csj[j] = ci;
      puv[j] = ci;
      hnprev[j] = 0.f;
    }
    __builtin_amdgcn_s_setprio(1);  // compute waves favored over helpers
  } else {
    stx(&xt[(R0 + 2) % 3][0]);   // stage x(R0+2)
    ldg();                       // px = x(R0+3)
  }
  __syncthreads();  // S3: xt(R0+2) visible

  // rotating pointers (uniform)
  unsigned char* Pc = &Pbuf[R0 & 1][0];        // written this step
  unsigned char* Pp = &Pbuf[(R0 + 1) & 1][0];  // read this step
  unsigned char* xA = &xt[(R0 + 2) % 3][0];    // in-flight (x(d+2))
  unsigned char* xB = &xt[R0 % 3][0];          // stx write (x(d+3))
  unsigned char* xC = &xt[(R0 + 1) % 3][0];    // compute shadow read x(d+1)

  for (int d = R0; d <= D1; ++d) {
    if (isComp) {
      // ---- post-barrier critical region: P read -> 8 dual 2-deep chains
      bf16x8 pa0 = *(const bf16x8*)(Pp + o_ph0);
      bf16x8 pa1 = *(const bf16x8*)(Pp + o_ph1);
      // x-frags for the tail shadow (xC stable all step)
      bf16x8 a0 = *(const bf16x8*)(xC + o_ax0);
      bf16x8 a1 = *(const bf16x8*)(xC + o_ax1);
      // guard read (tag d); gh2 carried from last step's gh1
      const float gh1 = bfbits2f(*(const unsigned short*)(gbh + (d & 7) * 128 + u * 2));
      const float gh2 = ghp;
      const float gc1 = gbc[(d & 7) * 64 + u];
      f32x4 aL[4];
#pragma unroll
      for (int t = 0; t < 4; ++t)
        zacc[t] = __builtin_amdgcn_mfma_f32_16x16x32_bf16(pa0, wrh[t][0], zacc[t], 0, 0, 0);
#pragma unroll
      for (int t = 0; t < 4; ++t)
        aL[t] = __builtin_amdgcn_mfma_f32_16x16x32_bf16(pa0, wrl[t][0], zerov, 0, 0, 0);
#pragma unroll
      for (int t = 0; t < 4; ++t)
        zacc[t] = __builtin_amdgcn_mfma_f32_16x16x32_bf16(pa1, wrh[t][1], zacc[t], 0, 0, 0);
#pragma unroll
      for (int t = 0; t < 4; ++t)
        aL[t] = __builtin_amdgcn_mfma_f32_16x16x32_bf16(pa1, wrl[t][1], aL[t], 0, 0, 0);
#pragma unroll
      for (int t = 0; t < 4; ++t) zacc[t] = zacc[t] + aL[t];

      const bool pubW = (ch < NCH - 1) && (d >= R0 + 15);

      // ---- batched independent gate exp2s (fills trans pipe) ----
      float e1v[4], e2v[4], e3v[4], e4v[4];
#pragma unroll
      for (int j = 0; j < 4; ++j) {
        e1v[j] = __builtin_amdgcn_exp2f(-zacc[1][j]);  // zf
        e2v[j] = __builtin_amdgcn_exp2f(-zacc[0][j]);  // zi
        e3v[j] = __builtin_amdgcn_exp2f(zacc[2][j]);   // zg
        e4v[j] = __builtin_amdgcn_exp2f(-zacc[3][j]);  // zo
      }

      // ---- j=3 first (feeds publish + cross-row shuffles) ----
      float hcur[4], cnew[4];
      {
        const int cj = cbase - 3;
        const bool ok = ((unsigned)cj <= 127u);
        const float inv = (cj == 0) ? 1.f : (1.f / 3.f);  // lm>=3 -> r>0
        const float cpj = csj[3] * inv;
        const float A = 1.f + e1v[3];
        const float BC = (1.f + e2v[3]) * (1.f + e3v[3]);
        float cn = (cpj * BC + (e3v[3] - 1.f) * A) *
                   __builtin_amdgcn_rcpf(A * BC);
        const float e5 = __builtin_amdgcn_exp2f(2.f * L2E * cn);
        float hn = (e5 - 1.f) *
                   __builtin_amdgcn_rcpf((1.f + e4v[3]) * (1.f + e5));
        if (pubW && hi16 == 3) {  // DIRECT publish: pack + store, no gate
          u64 v = ((u64)(unsigned short)d << 48) | ((u64)f2bfbits(hn) << 32) |
                  (u64)__float_as_uint(cn);
          u64* dst = ring + ((linkUp * RDEPTH + (d & (RDEPTH - 1))) << 6) + u;
          __hip_atomic_store(dst, v, __ATOMIC_RELAXED,
                             __HIP_MEMORY_SCOPE_AGENT);
        }
        hcur[3] = ok ? hn : 0.f;
        cnew[3] = ok ? cn : 0.f;
      }
      // issue cross-row shuffles early (hide ds_bpermute under j=2..0)
      const unsigned pk =
          ((unsigned)f2bfbits(hcur[3]) << 16) | f2bfbits(hnprev[3]);
      const unsigned pku = __shfl((int)pk, (L - 16) & 63);
      const float up_c = __shfl(cnew[3], (L - 16) & 63);

      // ---- j=2..0 epilogue with INTERLEAVED P-row writes:
      //      row j+1 is stored as soon as hcur[j] lands ----
#pragma unroll
      for (int jj = 0; jj < 3; ++jj) {
        const int j = 2 - jj;
        const int cj = cbase - j;
        const bool ok = ((unsigned)cj <= 127u);
        const float inv =
            (cj == 0 || (j == 0 && R0 == 0 && hi16 == 0)) ? 1.f : (1.f / 3.f);
        const float cpj = csj[j] * inv;
        const float A = 1.f + e1v[j];
        const float BC = (1.f + e2v[j]) * (1.f + e3v[j]);
        float cn = (cpj * BC + (e3v[j] - 1.f) * A) *
                   __builtin_amdgcn_rcpf(A * BC);
        const float e5 = __builtin_amdgcn_exp2f(2.f * L2E * cn);
        float hn = (e5 - 1.f) *
                   __builtin_amdgcn_rcpf((1.f + e4v[j]) * (1.f + e5));
        hcur[j] = ok ? hn : 0.f;
        cnew[j] = ok ? cn : 0.f;
        // write P row j+1 (needs hcur[j+1] (done), hcur[j], hnprev[j])
        const float sP1 = (cbase + 1 == j + 1) ? 1.f : (1.f / 3.f);
        *(unsigned short*)(Pc + o_pw[j + 1]) =
            f2bfbits(sP1 * (hcur[j] + hcur[j + 1] + hnprev[j]));
        csj[j + 1] = cnew[j] + cnew[j + 1] + puv[j + 1];
        puv[j + 1] = cnew[j];
      }
      // row 0 (needs shuffle results / guards)
      {
        const float up_h = bfbits2f((unsigned short)(pku >> 16));
        const float up_hp = bfbits2f((unsigned short)(pku & 0xffff));
        const float hup = hi16 ? up_h : gh1;
        const float hulp = hi16 ? up_hp : gh2;
        const float sP0 =
            ((cbase + 1 == 0) || (R0 == 0 && hi16 == 0)) ? 1.f : (1.f / 3.f);
        *(unsigned short*)(Pc + o_pw[0]) =
            f2bfbits(sP0 * (hup + hcur[0] + hulp));
        const float cun = hi16 ? up_c : gc1;
        csj[0] = cun + cnew[0] + puv[0];
        puv[0] = cun;
      }
      ghp = gh1;

      // ---- out stores (pure sinks, off the lgkm path) ----
#pragma unroll
      for (int j = 0; j < 4; ++j) {
        if ((unsigned)(cbase - j) <= 127u) out[oidx[j]] = hcur[j];
        hnprev[j] = hcur[j];
        oidx[j] += oStep;
      }
      ++cbase;

      // ---- tail shadow: accA(d+1) = b + x(d+1)@Wk (C=bvec direct) ----
#pragma unroll
      for (int t = 0; t < 4; ++t) {
        zacc[t] = __builtin_amdgcn_mfma_f32_16x16x32_bf16(a0, wkh[t][0], bvec[t], 0, 0, 0);
        zacc[t] = __builtin_amdgcn_mfma_f32_16x16x32_bf16(a1, wkh[t][1], zacc[t], 0, 0, 0);
      }
    } else {
      // ---- helpers: poll/gate ISSUE -> stage -> RESOLVE ----
      const bool meAct = (ch > 0) && (wq == ((d - R0) & 1));
      const int q = d + 1;  // lookahead 1
      const bool qLive = meAct && (q >= R0 + 1) && (q <= R0 + 126);
      const u64* qs = ring + ((linkDn * RDEPTH + (q & (RDEPTH - 1))) << 6) + L;
      u64 qv = 0;
      if (qLive)
        qv = __hip_atomic_load(qs, __ATOMIC_RELAXED, __HIP_MEMORY_SCOPE_AGENT);
      // wave 6: pre-validate ring-wrap gate for tag d+1
      const int nt = d + 1;
      const bool gatev = (wq == 2) && (ch < NCH - 1) && (nt <= D1) &&
                         (nt >= R0 + 15 + RDEPTH);
      int progNow = gateSeen;
      if (gatev && gateSeen < nt - RDEPTH)
        progNow = __hip_atomic_load(&prog[linkUp * 16], __ATOMIC_RELAXED,
                                    __HIP_MEMORY_SCOPE_AGENT);

      stx(xB);  // x(d+3)
      ldg();    // px = x(d+4)

      if (qLive) {
        int spin = 0;
        while ((unsigned short)(qv >> 48) != (unsigned short)q &&
               spin < (1 << 22)) {
          ++spin;
          __builtin_amdgcn_s_sleep(1);
          qv = __hip_atomic_load(qs, __ATOMIC_RELAXED,
                                 __HIP_MEMORY_SCOPE_AGENT);
        }
        *(unsigned short*)(gbh + (q & 7) * 128 + L * 2) =
            (unsigned short)(qv >> 32);
        gbc[(q & 7) * 64 + L] = __uint_as_float((unsigned)qv);
      }
      if (meAct && L == 0)
        __hip_atomic_store(&prog[linkDn * 16], min(d + 1, R0 + 126),
                           __ATOMIC_RELAXED, __HIP_MEMORY_SCOPE_AGENT);
      if (gatev) {
        if (progNow > gateSeen) gateSeen = progNow;
        int spin = 0;
        while (gateSeen < nt - RDEPTH && spin < (1 << 22)) {
          ++spin;
          __builtin_amdgcn_s_sleep(1);
          gateSeen = __hip_atomic_load(&prog[linkUp * 16], __ATOMIC_RELAXED,
                                       __HIP_MEMORY_SCOPE_AGENT);
        }
      }
    }

    // rotate buffers (uniform, cheap pointer swaps)
    {
      unsigned char* t0 = xA; xA = xB; xB = xC; xC = t0;
      unsigned char* t1 = Pc; Pc = Pp; Pp = t1;
    }
    barrier_lds();  // single barrier: all LDS writes -> next step's reads
  }
}

extern "C" void kernel_launch(void* const* d_in, const int* in_sizes, int n_in,
                              void* d_out, int out_size, void* d_ws, size_t ws_size,
                              hipStream_t stream) {
  const float* x = (const float*)d_in[0];
  const float* Wk = (const float*)d_in[1];
  const float* Wr = (const float*)d_in[2];
  const float* b = (const float*)d_in[3];
  float* out = (float*)d_out;
  // reset ring tags + progress flags every launch (graph-replay determinism)
  hipMemsetAsync(d_ws, 0, PROG_OFF + NLINK * 16 * sizeof(int), stream);
  hipLaunchKernelGGL(mdrnn_kernel, dim3(128), dim3(512), 0, stream, x, Wk, Wr,
                     b, out, (char*)d_ws);
}